// Round 4
// baseline (229.334 us; speedup 1.0000x reference)
//
#include <hip/hip_runtime.h>
#include <stdint.h>

typedef short s16x8 __attribute__((ext_vector_type(8)));
typedef float f32x4 __attribute__((ext_vector_type(4)));

__device__ __forceinline__ float bits2f(unsigned short u) {
    union { unsigned int i; float f; } c; c.i = ((unsigned int)u) << 16; return c.f;
}
__device__ __forceinline__ unsigned short f2bits(float f) {
    union { float f; unsigned int i; } c; c.f = f;
    unsigned int x = c.i;
    unsigned int r = (x + 0x7FFFu + ((x >> 16) & 1u)) >> 16;
    return (unsigned short)r;
}
__device__ __forceinline__ unsigned int pack2(float a, float b) {
    return (unsigned int)f2bits(a) | ((unsigned int)f2bits(b) << 16);
}

// ---------------------------------------------------------------------------
// f32 -> bf16 bulk convert; n8 = n/8
__global__ __launch_bounds__(256) void k_cvt(
    const float* __restrict__ src, unsigned short* __restrict__ dst, int n8)
{
    int i = blockIdx.x * 256 + threadIdx.x;
    if (i >= n8) return;
    const float* s = src + (size_t)i * 8;
    float4 a = *(const float4*)s, b = *(const float4*)(s + 4);
    unsigned int q[4] = { pack2(a.x, a.y), pack2(a.z, a.w), pack2(b.x, b.y), pack2(b.z, b.w) };
    *(s16x8*)(dst + (size_t)i * 8) = *(s16x8*)q;
}

// ---------------------------------------------------------------------------
// transpose (WqT only, 256x256 bf16): dst[dr][c] = src[c][dr]
__global__ __launch_bounds__(256) void k_transpose(
    const unsigned short* __restrict__ src, unsigned short* __restrict__ dst,
    int RS, int DS)
{
    int dr = blockIdx.x * 256 + threadIdx.x;
    int c0 = blockIdx.y * 8;
    __align__(16) unsigned short tmp[8];
#pragma unroll
    for (int j = 0; j < 8; ++j) tmp[j] = src[(size_t)(c0 + j) * RS + dr];
    *(s16x8*)(dst + (size_t)dr * DS + c0) = *(s16x8*)tmp;
}

// ---------------------------------------------------------------------------
// gemm_bt: C[m][n] = sum_k A[m][k] * Bt[n][k]; A bf16, Bt bf16 or f32 (BF32).
// BM=BN=128, BK=64, block=256. bz: b=bz&15, kc=bz>>4; K-origin = kc*Kstep.
template <int BF32>
__global__ __launch_bounds__(256) void gemm_bt(
    const unsigned short* __restrict__ A, const void* __restrict__ Bt,
    unsigned short* __restrict__ C,
    int K, int Kstep, int lda, int ldb, int ldc,
    long Abs, long Bbs, long Cbs)
{
    __shared__ unsigned short As[128][72];
    __shared__ unsigned short Bs[128][72];
    int bz = blockIdx.z;
    int b = bz & 15, kc = bz >> 4;
    int m0 = blockIdx.y * 128, n0 = blockIdx.x * 128;
    const unsigned short* Ab = A + (size_t)b * Abs + (size_t)m0 * lda + (size_t)kc * Kstep;
    size_t boff = (size_t)b * Bbs + (size_t)n0 * ldb + (size_t)kc * Kstep;
    int t = threadIdx.x;
    int w = t >> 6, l = t & 63, lm = l & 15, lq = l >> 4;
    int mw = (w >> 1) * 64, nw = (w & 1) * 64;

    f32x4 acc[4][4];
    f32x4 zero = {0.f, 0.f, 0.f, 0.f};
#pragma unroll
    for (int i = 0; i < 4; ++i)
#pragma unroll
        for (int j = 0; j < 4; ++j) acc[i][j] = zero;

    for (int kk = 0; kk < K; kk += 64) {
#pragma unroll
        for (int i = 0; i < 4; ++i) {
            int idx = t + i * 256;
            int r = idx >> 3, ch = idx & 7;
            *(s16x8*)&As[r][ch * 8] = *(const s16x8*)(Ab + (size_t)r * lda + kk + ch * 8);
            if (BF32) {
                const float* bp = (const float*)Bt + boff + (size_t)r * ldb + kk + ch * 8;
                float4 v0 = *(const float4*)bp, v1 = *(const float4*)(bp + 4);
                unsigned int q[4] = { pack2(v0.x, v0.y), pack2(v0.z, v0.w),
                                      pack2(v1.x, v1.y), pack2(v1.z, v1.w) };
                *(s16x8*)&Bs[r][ch * 8] = *(s16x8*)q;
            } else {
                const unsigned short* bp = (const unsigned short*)Bt + boff + (size_t)r * ldb + kk + ch * 8;
                *(s16x8*)&Bs[r][ch * 8] = *(const s16x8*)bp;
            }
        }
        __syncthreads();
#pragma unroll
        for (int ks = 0; ks < 2; ++ks) {
            s16x8 af[4], bfr[4];
#pragma unroll
            for (int mi = 0; mi < 4; ++mi) af[mi]  = *(const s16x8*)&As[mw + mi * 16 + lm][ks * 32 + lq * 8];
#pragma unroll
            for (int ni = 0; ni < 4; ++ni) bfr[ni] = *(const s16x8*)&Bs[nw + ni * 16 + lm][ks * 32 + lq * 8];
#pragma unroll
            for (int mi = 0; mi < 4; ++mi)
#pragma unroll
                for (int ni = 0; ni < 4; ++ni)
                    acc[mi][ni] = __builtin_amdgcn_mfma_f32_16x16x32_bf16(af[mi], bfr[ni], acc[mi][ni], 0, 0, 0);
        }
        __syncthreads();
    }

    unsigned short* Cb = C + (size_t)bz * Cbs;
#pragma unroll
    for (int mi = 0; mi < 4; ++mi)
#pragma unroll
        for (int r = 0; r < 4; ++r) {
            int m = m0 + mw + mi * 16 + lq * 4 + r;
#pragma unroll
            for (int ni = 0; ni < 4; ++ni) {
                int n = n0 + nw + ni * 16 + lm;
                Cb[(size_t)m * ldc + n] = f2bits(acc[mi][ni][r]);
            }
        }
}

// ---------------------------------------------------------------------------
// gemm_bn: C[m][n] = sum_k A[m][k] * B[k][n]; A bf16, B f32 n-contiguous.
// EPI==0: C is bf16.  EPI==1: C is f32, C = gamma[m]*(acc+bias[m]) + Xres[m][n].
template <int EPI>
__global__ __launch_bounds__(256) void gemm_bn(
    const unsigned short* __restrict__ A, const float* __restrict__ B,
    void* __restrict__ C,
    int K, int lda, int ldb, int ldc,
    long Abs, long Bbs, long Cbs,
    const float* __restrict__ Xres,
    const float* __restrict__ gamma,
    const float* __restrict__ bias)
{
    __shared__ unsigned short As[128][72];
    __shared__ unsigned short Bs[64][130];
    int bz = blockIdx.z;
    int m0 = blockIdx.y * 128, n0 = blockIdx.x * 128;
    const unsigned short* Ab = A + (size_t)bz * Abs + (size_t)m0 * lda;
    const float* Bb = B + (size_t)bz * Bbs + n0;
    int t = threadIdx.x;
    int w = t >> 6, l = t & 63, lm = l & 15, lq = l >> 4;
    int mw = (w >> 1) * 64, nw = (w & 1) * 64;

    f32x4 acc[4][4];
    f32x4 zero = {0.f, 0.f, 0.f, 0.f};
#pragma unroll
    for (int i = 0; i < 4; ++i)
#pragma unroll
        for (int j = 0; j < 4; ++j) acc[i][j] = zero;

    for (int kk = 0; kk < K; kk += 64) {
#pragma unroll
        for (int i = 0; i < 4; ++i) {
            int idx = t + i * 256;
            int r = idx >> 3, ch = idx & 7;
            *(s16x8*)&As[r][ch * 8] = *(const s16x8*)(Ab + (size_t)r * lda + kk + ch * 8);
        }
#pragma unroll
        for (int i = 0; i < 4; ++i) {
            int idx = t + i * 256;
            int c = idx >> 4, cc = idx & 15;
            const float* bp = Bb + (size_t)(kk + c) * ldb + cc * 8;
            float4 v0 = *(const float4*)bp, v1 = *(const float4*)(bp + 4);
            unsigned int* q = (unsigned int*)&Bs[c][cc * 8];
            q[0] = pack2(v0.x, v0.y); q[1] = pack2(v0.z, v0.w);
            q[2] = pack2(v1.x, v1.y); q[3] = pack2(v1.z, v1.w);
        }
        __syncthreads();
#pragma unroll
        for (int ks = 0; ks < 2; ++ks) {
            s16x8 af[4];
#pragma unroll
            for (int mi = 0; mi < 4; ++mi) af[mi] = *(const s16x8*)&As[mw + mi * 16 + lm][ks * 32 + lq * 8];
#pragma unroll
            for (int ni = 0; ni < 4; ++ni) {
                s16x8 bfr;
#pragma unroll
                for (int j = 0; j < 8; ++j) bfr[j] = (short)Bs[ks * 32 + lq * 8 + j][nw + ni * 16 + lm];
#pragma unroll
                for (int mi = 0; mi < 4; ++mi)
                    acc[mi][ni] = __builtin_amdgcn_mfma_f32_16x16x32_bf16(af[mi], bfr, acc[mi][ni], 0, 0, 0);
            }
        }
        __syncthreads();
    }

#pragma unroll
    for (int mi = 0; mi < 4; ++mi)
#pragma unroll
        for (int r = 0; r < 4; ++r) {
            int m = m0 + mw + mi * 16 + lq * 4 + r;
            float g = 0.f, bo = 0.f;
            if (EPI == 1) { g = gamma[m]; bo = bias[m]; }
#pragma unroll
            for (int ni = 0; ni < 4; ++ni) {
                int n = n0 + nw + ni * 16 + lm;
                size_t idx = (size_t)m * ldc + n;
                float v = acc[mi][ni][r];
                if (EPI == 1) {
                    float* Cb = (float*)C + (size_t)bz * Cbs;
                    Cb[idx] = g * (v + bo) + Xres[(size_t)bz * Cbs + idx];
                } else {
                    unsigned short* Cb = (unsigned short*)C + (size_t)bz * Cbs;
                    Cb[idx] = f2bits(v);
                }
            }
        }
}

// ---------------------------------------------------------------------------
// softmax over n (4096) for each of 4096 rows of kbuf (bf16)
__global__ __launch_bounds__(256) void k_softmax(unsigned short* __restrict__ kbuf)
{
    unsigned short* p = kbuf + (size_t)blockIdx.x * 4096;
    int t = threadIdx.x;
    __shared__ float red[4];

    s16x8 r0 = *(const s16x8*)(p + t * 16);
    s16x8 r1 = *(const s16x8*)(p + t * 16 + 8);
    float v[16];
    float m = -1e30f;
#pragma unroll
    for (int i = 0; i < 8; ++i) { v[i] = bits2f((unsigned short)r0[i]); v[8 + i] = bits2f((unsigned short)r1[i]); }
#pragma unroll
    for (int i = 0; i < 16; ++i) m = fmaxf(m, v[i]);
#pragma unroll
    for (int off = 32; off >= 1; off >>= 1) m = fmaxf(m, __shfl_xor(m, off));
    if ((t & 63) == 0) red[t >> 6] = m;
    __syncthreads();
    m = fmaxf(fmaxf(red[0], red[1]), fmaxf(red[2], red[3]));
    __syncthreads();

    float s = 0.f;
#pragma unroll
    for (int i = 0; i < 16; ++i) { v[i] = __expf(v[i] - m); s += v[i]; }
#pragma unroll
    for (int off = 32; off >= 1; off >>= 1) s += __shfl_xor(s, off);
    if ((t & 63) == 0) red[t >> 6] = s;
    __syncthreads();
    s = red[0] + red[1] + red[2] + red[3];
    float inv = 1.0f / s;

    __align__(16) unsigned short otmp[16];
#pragma unroll
    for (int i = 0; i < 16; ++i) otmp[i] = f2bits(v[i] * inv);
    *(s16x8*)(p + t * 16) = *(s16x8*)(otmp);
    *(s16x8*)(p + t * 16 + 8) = *(s16x8*)(otmp + 8);
}

// ---------------------------------------------------------------------------
// G[b][i] = sum_{kc<8} Gp[kc*16+b][i]
__global__ __launch_bounds__(256) void k_gred(
    const unsigned short* __restrict__ Gp, unsigned short* __restrict__ G)
{
    int gid = blockIdx.x * 256 + threadIdx.x;   // [0, 131072)
    int b = gid >> 13;
    size_t i8 = (size_t)(gid & 8191) * 8;
    float s[8] = {0.f, 0.f, 0.f, 0.f, 0.f, 0.f, 0.f, 0.f};
#pragma unroll
    for (int kc = 0; kc < 8; ++kc) {
        s16x8 v = *(const s16x8*)(Gp + (size_t)(kc * 16 + b) * 65536 + i8);
#pragma unroll
        for (int j = 0; j < 8; ++j) s[j] += bits2f((unsigned short)v[j]);
    }
    __align__(16) unsigned short tmp[8];
#pragma unroll
    for (int j = 0; j < 8; ++j) tmp[j] = f2bits(s[j]);
    *(s16x8*)(G + (size_t)b * 65536 + i8) = *(s16x8*)tmp;
}

// ---------------------------------------------------------------------------
// per (b,h): ctx[d][e] = sum_c G[b][h*64+d][c] * Wv[h*64+e][c]  (K=256)
// then      W2[b][o][h*64+d] = sum_e w_out[o][h*64+e] * ctx[d][e] (K=64)
__global__ __launch_bounds__(256) void k_ctxw2(
    const unsigned short* __restrict__ G, const unsigned short* __restrict__ wb,
    const unsigned short* __restrict__ wob, unsigned short* __restrict__ W2)
{
    __shared__ unsigned short ctxs[64][72];
    int h = blockIdx.x, b = blockIdx.y;
    int t = threadIdx.x, w = t >> 6, l = t & 63, lm = l & 15, lq = l >> 4;
    const unsigned short* Gb = G + (size_t)b * 65536 + (size_t)(h * 64) * 256;
    const unsigned short* Wv = wb + 131072 + (size_t)(h * 64) * 256;
    f32x4 zero = {0.f, 0.f, 0.f, 0.f};

    f32x4 acc[4];
#pragma unroll
    for (int i = 0; i < 4; ++i) acc[i] = zero;
    for (int kk = 0; kk < 256; kk += 32) {
        s16x8 a = *(const s16x8*)(Gb + (size_t)(w * 16 + lm) * 256 + kk + lq * 8);
#pragma unroll
        for (int ni = 0; ni < 4; ++ni) {
            s16x8 bb = *(const s16x8*)(Wv + (size_t)(ni * 16 + lm) * 256 + kk + lq * 8);
            acc[ni] = __builtin_amdgcn_mfma_f32_16x16x32_bf16(a, bb, acc[ni], 0, 0, 0);
        }
    }
#pragma unroll
    for (int ni = 0; ni < 4; ++ni)
#pragma unroll
        for (int r = 0; r < 4; ++r)
            ctxs[w * 16 + lq * 4 + r][ni * 16 + lm] = f2bits(acc[ni][r]);
    __syncthreads();

    f32x4 acc2[4][4];
#pragma unroll
    for (int i = 0; i < 4; ++i)
#pragma unroll
        for (int j = 0; j < 4; ++j) acc2[i][j] = zero;
#pragma unroll
    for (int ks = 0; ks < 2; ++ks) {
        s16x8 af[4], bfr[4];
#pragma unroll
        for (int mi = 0; mi < 4; ++mi)
            af[mi] = *(const s16x8*)(wob + (size_t)(w * 64 + mi * 16 + lm) * 256 + h * 64 + ks * 32 + lq * 8);
#pragma unroll
        for (int ni = 0; ni < 4; ++ni) bfr[ni] = *(const s16x8*)&ctxs[ni * 16 + lm][ks * 32 + lq * 8];
#pragma unroll
        for (int mi = 0; mi < 4; ++mi)
#pragma unroll
            for (int ni = 0; ni < 4; ++ni)
                acc2[mi][ni] = __builtin_amdgcn_mfma_f32_16x16x32_bf16(af[mi], bfr[ni], acc2[mi][ni], 0, 0, 0);
    }
    unsigned short* W2b = W2 + (size_t)b * 65536;
#pragma unroll
    for (int mi = 0; mi < 4; ++mi)
#pragma unroll
        for (int r = 0; r < 4; ++r) {
            int o = w * 64 + mi * 16 + lq * 4 + r;
#pragma unroll
            for (int ni = 0; ni < 4; ++ni)
                W2b[(size_t)o * 256 + h * 64 + ni * 16 + lm] = f2bits(acc2[mi][ni][r]);
        }
}

// ---------------------------------------------------------------------------
extern "C" void kernel_launch(void* const* d_in, const int* in_sizes, int n_in,
                              void* d_out, int out_size, void* d_ws, size_t ws_size,
                              hipStream_t stream)
{
    (void)in_sizes; (void)n_in; (void)out_size; (void)ws_size;
    const float* x      = (const float*)d_in[0]; // [16][256][4096] f32
    const float* w_qkv  = (const float*)d_in[1]; // [768][256] f32
    const float* w_out  = (const float*)d_in[2]; // [256][256] f32
    const float* b_out  = (const float*)d_in[3]; // [256] f32
    const float* gamma  = (const float*)d_in[4]; // [256] f32
    unsigned short* kbuf = (unsigned short*)d_out; // first 32MB of d_out = bf16 k scratch
    // final output: f32, written by K5 over the full 64MB

    char* ws = (char*)d_ws;                                       // total ws use: 23,724,032 B
    unsigned short* Gp  = (unsigned short*)(ws);                  // [128][256][256] bf16 = 16,777,216 B
    unsigned short* G   = (unsigned short*)(ws + 16777216);       //  2,097,152 B
    unsigned short* W2  = (unsigned short*)(ws + 18874368);       //  2,097,152 B
    unsigned short* W3  = (unsigned short*)(ws + 20971520);       //  2,097,152 B
    unsigned short* WqT = (unsigned short*)(ws + 23068672);       //    131,072 B
    unsigned short* wb  = (unsigned short*)(ws + 23199744);       // w_qkv bf16: 393,216 B
    unsigned short* wob = (unsigned short*)(ws + 23592960);       // w_out bf16: 131,072 B

    // convert weights to bf16
    k_cvt<<<dim3(96), 256, 0, stream>>>(w_qkv, wb, 24576);
    k_cvt<<<dim3(32), 256, 0, stream>>>(w_out, wob, 8192);

    // WqT[c][hd] = wq[hd][c]
    k_transpose<<<dim3(1, 32, 1), 256, 0, stream>>>(wb, WqT, 256, 256);

    // K1: k = Wk @ x -> kbuf (bf16)  (M=256, N=4096, K=256)
    gemm_bn<0><<<dim3(32, 2, 16), 256, 0, stream>>>(
        wb + 65536, x, kbuf, 256, 256, 4096, 4096,
        0L, 1048576L, 1048576L, nullptr, nullptr, nullptr);

    // K2: softmax rows of k
    k_softmax<<<dim3(4096), 256, 0, stream>>>(kbuf);

    // KG: Gp[kc*16+b] = softk_b[:, chunk] @ x_b[:, chunk]^T  (K-split x8)
    gemm_bt<1><<<dim3(2, 2, 128), 256, 0, stream>>>(
        kbuf, x, Gp, 512, 512, 4096, 4096, 256,
        1048576L, 1048576L, 65536L);

    // G = sum_kc Gp
    k_gred<<<dim3(512), 256, 0, stream>>>(Gp, G);

    // ctx + W2 fused per (b,h)
    k_ctxw2<<<dim3(4, 16), 256, 0, stream>>>(G, wb, wob, W2);

    // W3[b] = W2[b] @ Wq
    gemm_bt<0><<<dim3(2, 2, 16), 256, 0, stream>>>(
        W2, WqT, W3, 256, 0, 256, 256, 256,
        65536L, 0L, 65536L);

    // K5: out(f32) = gamma*(W3 @ x + b_out) + x
    gemm_bn<1><<<dim3(32, 2, 16), 256, 0, stream>>>(
        W3, x, d_out, 256, 256, 4096, 4096,
        65536L, 1048576L, 1048576L, x, gamma, b_out);
}